// Round 1
// 280.173 us; speedup vs baseline: 1.0491x; 1.0491x over previous
//
#include <hip/hip_runtime.h>

// e3nn fully-connected tensor product, v4: f16 MFMA 32x32x16 + double-buffered
// weight staging. One wave owns 32 rows (lane&31 = its row). x1/x2 features
// live in registers (loaded once, coalesced float4); LDS holds TWO 16-u
// half-tensors (2 x 32 KB): stage s+1 is prefetched via global_load_lds while
// stage s computes, with ONE __syncthreads per stage (its implicit
// vmcnt(0)/lgkmcnt(0) drain covers both the loads-landed and the
// reads-done-before-overwrite hazards).

typedef _Float16 f16;
typedef f16 f16x8 __attribute__((ext_vector_type(8)));
typedef float f32x16 __attribute__((ext_vector_type(16)));

#define MFMA32(a, b, c) __builtin_amdgcn_mfma_f32_32x32x16_f16(a, b, c, 0, 0, 0)

// A000 = A011 = A101 = A111 = 1/sqrt(2048); A110 = 1/sqrt(6144)
#define SC_COMMON 0.022097086912079608f
#define SC_110    0.012757759118834242f

// ---------------- weight prep ------------------------------------------------
// ws order: c0=w000, c1=w110, c2=w011, c3=w101, c4=w111 (scales folded).
// B-frag (32x32x16): lane holds B[k=(lane>>5)*8+j][n=lane&31], K-chunk vh.
// idx = ((c*32 + u)*2 + vh)*512 + lane*8 + j
//   element = sc * W[u][ v = vh*16 + (lane>>5)*8 + j ][ w = lane&31 ]
__global__ void prep_w(const float* __restrict__ w000, const float* __restrict__ w011,
                       const float* __restrict__ w101, const float* __restrict__ w110,
                       const float* __restrict__ w111, f16* __restrict__ wsW)
{
    int flat = blockIdx.x * 256 + threadIdx.x;
    if (flat >= 5 * 32768) return;
    int c    = flat >> 15;
    int r    = flat & 32767;
    int j    = r & 7;
    int lane = (r >> 3) & 63;
    int vh   = (r >> 9) & 1;
    int u    = r >> 10;
    int v = vh * 16 + ((lane >> 5) << 3) + j;
    int w = lane & 31;
    const float* src; float sc;
    switch (c) {
        case 0: src = w000; sc = SC_COMMON; break;
        case 1: src = w110; sc = SC_110;    break;
        case 2: src = w011; sc = SC_COMMON; break;
        case 3: src = w101; sc = SC_COMMON; break;
        default: src = w111; sc = SC_COMMON; break;
    }
    wsW[flat] = (f16)(sc * src[u * 1024 + v * 32 + w]);
}

// ---------------- main kernel ------------------------------------------------
// MODE: 0 = w000 (s*s), 1 = w110 (vec dot), 2 = w011 (p011, 3 acc),
//       3 = w101 (p101, 3 acc), 4 = w111 (cross, 3 acc)
template <int U0, int MODE, int NA>
__device__ __forceinline__ void do_stage(f32x16 (&acc)[NA],
                                         const f16* __restrict__ ldsW,
                                         const f16x8 (&f1g)[4][4],
                                         const f16x8 (&f2g)[4][2], int lane)
{
#pragma unroll
    for (int ul = 0; ul < 16; ++ul) {
        const int u = U0 + ul;
#pragma unroll
        for (int vh = 0; vh < 2; ++vh) {
            f16x8 b = *(const f16x8*)(ldsW + ul * 1024 + vh * 512 + lane * 8);
            if (MODE == 0) {
                f16x8 a = f1g[0][u >> 3][u & 7] * f2g[0][vh];
                acc[0] = MFMA32(a, b, acc[0]);
            } else if (MODE == 1) {
                f16x8 a = f1g[1][u >> 3][u & 7] * f2g[1][vh];
                a += f1g[2][u >> 3][u & 7] * f2g[2][vh];
                a += f1g[3][u >> 3][u & 7] * f2g[3][vh];
                acc[0] = MFMA32(a, b, acc[0]);
            } else if (MODE == 2) {
#pragma unroll
                for (int j = 0; j < 3; ++j) {
                    f16x8 a = f1g[0][u >> 3][u & 7] * f2g[1 + j][vh];
                    acc[j] = MFMA32(a, b, acc[j]);
                }
            } else if (MODE == 3) {
#pragma unroll
                for (int j = 0; j < 3; ++j) {
                    f16x8 a = f1g[1 + j][u >> 3][u & 7] * f2g[0][vh];
                    acc[j] = MFMA32(a, b, acc[j]);
                }
            } else {
                // cross: k0:(i=1,j=2)->arrs(2,3); k1:(2,0)->(3,1); k2:(0,1)->(1,2)
#pragma unroll
                for (int k = 0; k < 3; ++k) {
                    const int P = (k == 0) ? 2 : (k == 1) ? 3 : 1;
                    const int Q = (k == 0) ? 3 : (k == 1) ? 1 : 2;
                    f16x8 a = f1g[P][u >> 3][u & 7] * f2g[Q][vh]
                            - f1g[Q][u >> 3][u & 7] * f2g[P][vh];
                    acc[k] = MFMA32(a, b, acc[k]);
                }
            }
        }
    }
}

__global__ __launch_bounds__(256, 2)
void tp_main(const float* __restrict__ x1, const float* __restrict__ x2,
             const f16* __restrict__ wsW, float* __restrict__ out)
{
    __shared__ __align__(16) f16 ldsW[2][16384];  // 64 KB: double-buffered halves

    const int tid = threadIdx.x, lane = tid & 63, wv = tid >> 6;
    const int rowBase = blockIdx.x * 128 + wv * 32;
    const int mrow = lane & 31;          // this lane's row (A and C/D)
    const int half = lane >> 5;          // k-group
    const int klo = half * 8;
    const float4* x1r4 = (const float4*)(x1 + (size_t)(rowBase + mrow) * 128);
    const float4* x2r4 = (const float4*)(x2 + (size_t)(rowBase + mrow) * 128);

    // Prefetch issue: stage s (s = c*2+h, s in [0,10)) lives in buffer s&1.
    auto issue = [&](int buf, int s) {
        const f16* src = wsW + s * 16384;
        f16* dst = &ldsW[buf][0];
#pragma unroll
        for (int it = 0; it < 8; ++it) {
            int o = (it * 256 + tid) * 8;
            __builtin_amdgcn_global_load_lds(
                (const __attribute__((address_space(1))) void*)(src + o),
                (__attribute__((address_space(3))) void*)(dst + o), 16, 0, 0);
        }
    };

    // Stage 0 in flight while we build the register fragments.
    issue(0, 0);

    // ---- f1: all 128 features of my row, f16, [arr][u] ----
    f16x8 f1g[4][4];
    {
        float b0[32];
#pragma unroll
        for (int g = 0; g < 8; ++g) ((float4*)b0)[g] = x1r4[g];
#pragma unroll
        for (int g = 0; g < 4; ++g)
#pragma unroll
            for (int j = 0; j < 8; ++j) f1g[0][g][j] = (f16)b0[g * 8 + j];
        float b1[96];
#pragma unroll
        for (int g = 0; g < 24; ++g) ((float4*)b1)[g] = x1r4[8 + g];
#pragma unroll
        for (int i = 0; i < 3; ++i)
#pragma unroll
            for (int g = 0; g < 4; ++g)
#pragma unroll
                for (int j = 0; j < 8; ++j)
                    f1g[1 + i][g][j] = (f16)b1[3 * (g * 8 + j) + i];
    }

    // ---- f2: my row's k-slice: v = vh*16 + klo + j, [arr][vh] ----
    f16x8 f2g[4][2];
    {
        float c0[16];
#pragma unroll
        for (int g = 0; g < 2; ++g) ((float4*)c0)[g]     = x2r4[klo / 4 + g];
#pragma unroll
        for (int g = 0; g < 2; ++g) ((float4*)c0)[2 + g] = x2r4[4 + klo / 4 + g];
#pragma unroll
        for (int vh = 0; vh < 2; ++vh)
#pragma unroll
            for (int j = 0; j < 8; ++j) f2g[0][vh][j] = (f16)c0[vh * 8 + j];
        // vec spans: floats [32+3*klo, +24) and [80+3*klo, +24), both 16B-aligned
        float c1[48];
        const int base1 = (32 + 3 * klo) / 4;
#pragma unroll
        for (int g = 0; g < 6; ++g) ((float4*)c1)[g]     = x2r4[base1 + g];
#pragma unroll
        for (int g = 0; g < 6; ++g) ((float4*)c1)[6 + g] = x2r4[base1 + 12 + g];
#pragma unroll
        for (int i = 0; i < 3; ++i)
#pragma unroll
            for (int vh = 0; vh < 2; ++vh)
#pragma unroll
                for (int j = 0; j < 8; ++j)
                    f2g[1 + i][vh][j] = (f16)c1[vh * 24 + 3 * j + i];
    }

    __syncthreads();  // stage 0 landed (barrier drains vmcnt for all waves)

    // Pipeline: per stage, issue prefetch of s+1 into the other buffer, then
    // compute on buffer s&1, then ONE barrier. Overwrite hazard is covered by
    // the end-of-(s-1) barrier; loads-landed by the end-of-s barrier drain.

    // ================= out0: w000 + w110 (stages 0..3) =================
    {
        f32x16 acc[1] = {};
        issue(1, 1); do_stage<0,  0>(acc, ldsW[0], f1g, f2g, lane); __syncthreads();
        issue(0, 2); do_stage<16, 0>(acc, ldsW[1], f1g, f2g, lane); __syncthreads();
        issue(1, 3); do_stage<0,  1>(acc, ldsW[0], f1g, f2g, lane); __syncthreads();
        issue(0, 4); do_stage<16, 1>(acc, ldsW[1], f1g, f2g, lane); __syncthreads();
        // out0 stores issued at the start of stage 4 (after the barrier), so
        // their completion drain overlaps stage-4 compute.
        issue(1, 5);
#pragma unroll
        for (int reg = 0; reg < 16; ++reg) {
            int r = (reg & 3) + 8 * (reg >> 2) + 4 * half;
            out[(size_t)(rowBase + r) * 224 + mrow] = acc[0][reg];
        }
    }
    // ================= out1: w011 (p011) + w101 (p101) (stages 4..7) ========
    {
        f32x16 acc[3] = {};
        /* issue(1,5) already done */ do_stage<0,  2>(acc, ldsW[0], f1g, f2g, lane); __syncthreads();
        issue(0, 6); do_stage<16, 2>(acc, ldsW[1], f1g, f2g, lane); __syncthreads();
        issue(1, 7); do_stage<0,  3>(acc, ldsW[0], f1g, f2g, lane); __syncthreads();
        issue(0, 8); do_stage<16, 3>(acc, ldsW[1], f1g, f2g, lane); __syncthreads();
        issue(1, 9);
#pragma unroll
        for (int reg = 0; reg < 16; ++reg) {
            int r = (reg & 3) + 8 * (reg >> 2) + 4 * half;
            size_t base = (size_t)(rowBase + r) * 224 + 32 + 3 * mrow;
            out[base + 0] = acc[0][reg];
            out[base + 1] = acc[1][reg];
            out[base + 2] = acc[2][reg];
        }
    }
    // ================= out2: w111 (cross) (stages 8..9) =================
    {
        f32x16 acc[3] = {};
        /* issue(1,9) already done */ do_stage<0,  4>(acc, ldsW[0], f1g, f2g, lane); __syncthreads();
        do_stage<16, 4>(acc, ldsW[1], f1g, f2g, lane);
#pragma unroll
        for (int reg = 0; reg < 16; ++reg) {
            int r = (reg & 3) + 8 * (reg >> 2) + 4 * half;
            size_t base = (size_t)(rowBase + r) * 224 + 128 + 3 * mrow;
            out[base + 0] = acc[0][reg];
            out[base + 1] = acc[1][reg];
            out[base + 2] = acc[2][reg];
        }
    }
}

// ---------------- launch -----------------------------------------------------
extern "C" void kernel_launch(void* const* d_in, const int* in_sizes, int n_in,
                              void* d_out, int out_size, void* d_ws, size_t ws_size,
                              hipStream_t stream)
{
    const float* x1   = (const float*)d_in[0];
    const float* x2   = (const float*)d_in[1];
    const float* w000 = (const float*)d_in[2];
    const float* w011 = (const float*)d_in[3];
    const float* w101 = (const float*)d_in[4];
    const float* w110 = (const float*)d_in[5];
    const float* w111 = (const float*)d_in[6];
    float* out = (float*)d_out;
    f16* wsW = (f16*)d_ws;  // 5 * 32768 f16 = 320 KB

    hipLaunchKernelGGL(prep_w, dim3(640), dim3(256), 0, stream,
                       w000, w011, w101, w110, w111, wsW);

    int n = in_sizes[0] / 128;  // 131072 rows
    hipLaunchKernelGGL(tp_main, dim3(n / 128), dim3(256), 0, stream,
                       x1, x2, wsW, out);
}